// Round 5
// baseline (1447.245 us; speedup 1.0000x reference)
//
#include <hip/hip_runtime.h>
#include <hip/hip_bf16.h>

// GraphSAGE: out = normalize( [x, segsum(vals*x[cols], rows)] @ W^T + b )
// N=100000, E=1600000, IN_F=128, OUT_F=128.
//
// Round 5: edge-balanced fused kernel. Phase 1: block's edge range split into
// 16 equal chunks (one per 16-lane slot); 8 gathers in flight; accumulate
// straight into fp32 LDS tile via ds_add_f32. Phase 2: MFMA + bias + norm.
//
// ws layout:
//   [0    , ~400K)  row_ptr (int[N+1])
//   [448K , 512K)   Wf: fragment-major bf16 W, 4096 x 16B
//   [640K , +25.6M) xb: bf16(x), N x 128 (rows of 16 uint4)

typedef __bf16 bf16x8_t __attribute__((ext_vector_type(8)));
typedef float f32x4_t __attribute__((ext_vector_type(4)));
typedef float f32x2_t __attribute__((ext_vector_type(2)));

__device__ __forceinline__ unsigned int f32_to_bf16(float f) {
    unsigned int u = __float_as_uint(f);
    unsigned int r = u + 0x7fffu + ((u >> 16) & 1u);   // RNE (no NaN inputs)
    return r >> 16;
}
__device__ __forceinline__ unsigned int pack2(float a, float b) {
    return f32_to_bf16(a) | (f32_to_bf16(b) << 16);
}
__device__ __forceinline__ float bflo(unsigned int p) { return __uint_as_float(p << 16); }
__device__ __forceinline__ float bfhi(unsigned int p) { return __uint_as_float(p & 0xffff0000u); }

// --- K0: fused prep: xcast | rowptr | wcast (block-range split) ------------
__global__ void prep_kernel(const float* __restrict__ x, uint4* __restrict__ xb4,
                            const int* __restrict__ rows, int* __restrict__ row_ptr,
                            const float* __restrict__ W, uint4* __restrict__ Wf,
                            int Nn, int Ee, int xcast_blks, int rowptr_blks) {
    int blk = blockIdx.x;
    if (blk < xcast_blks) {
        int i = blk * 256 + threadIdx.x;
        if (i < Nn * 16) {
            const float4* xf = (const float4*)x;
            float4 f0 = xf[(size_t)i * 2];
            float4 f1 = xf[(size_t)i * 2 + 1];
            uint4 o;
            o.x = pack2(f0.x, f0.y); o.y = pack2(f0.z, f0.w);
            o.z = pack2(f1.x, f1.y); o.w = pack2(f1.z, f1.w);
            xb4[i] = o;
        }
    } else if (blk < xcast_blks + rowptr_blks) {
        int n = (blk - xcast_blks) * 256 + threadIdx.x;
        if (n <= Nn) {
            int lo = 0, hi = Ee;
            while (lo < hi) {
                int mid = (lo + hi) >> 1;
                if (rows[mid] < n) lo = mid + 1; else hi = mid;
            }
            row_ptr[n] = lo;
        }
    } else {
        int i = (blk - xcast_blks - rowptr_blks) * 256 + threadIdx.x;  // 0..4095
        int lane = i & 63, ks = (i >> 6) & 7, t = i >> 9;
        int row = t * 16 + (lane & 15);
        int col = ks * 32 + (lane >> 4) * 8;
        const float* p = W + (size_t)row * 256 + col;
        uint4 o;
        o.x = pack2(p[0], p[1]); o.y = pack2(p[2], p[3]);
        o.z = pack2(p[4], p[5]); o.w = pack2(p[6], p[7]);
        Wf[i] = o;
    }
}

// --- K1: fused agg + gemm + normalize --------------------------------------
// block = 256 thr = 16 slots of 16 lanes; 16 nodes/block (grid exact 6250).
// Phase 1: edge range [rp[0], rp[16]) split into 16 equal chunks; slot s
//   processes its chunk with 8 gathers in flight; per-edge node id via
//   register-cached scan of rpS[]; fp32 accumulate into LDS via atomicAdd.
// Phase 2: 16-row MFMA (self half from xb global, neighbor half from LDS
//   fp32 tile), 2 col-tiles per wave, cross-wave norm via LDS.
__global__ __launch_bounds__(256, 8) void fused_kernel(
        const int* __restrict__ row_ptr,
        const int* __restrict__ cols,
        const float* __restrict__ vals,
        const char* __restrict__ xbB,
        const bf16x8_t* __restrict__ Wf,
        const float* __restrict__ b,
        float* __restrict__ out, int Nn) {
    __shared__ float nbAcc[16 * 132];    // node stride 132 (pad: bank-spread)
    __shared__ int   rpS[17];
    __shared__ float __attribute__((aligned(16))) sqLDS[16][4];

    int tid  = threadIdx.x;
    int lane = tid & 63;
    int w    = tid >> 6;

    // zero the accumulator tile; load row_ptr window
    for (int i = tid; i < 16 * 132; i += 256) nbAcc[i] = 0.f;
    if (tid < 17) rpS[tid] = row_ptr[blockIdx.x * 16 + tid];
    __syncthreads();

    // ---------------- phase 1: aggregate (edge-balanced) ----------------
    {
        int sid = tid >> 4;          // slot 0..15
        int l   = tid & 15;          // feature chunk [8l, 8l+8)
        unsigned loff = (unsigned)l << 4;
        int E0 = rpS[0], E1 = rpS[16];
        int chunk = (E1 - E0 + 15) >> 4;
        int e_begin = E0 + sid * chunk;
        int e_end   = min(e_begin + chunk, E1);

        // find node of e_begin
        int cur = 0;
        while (cur < 15 && e_begin >= rpS[cur + 1]) cur++;
        int rp_next = rpS[cur + 1];
        float* dst = nbAcc + cur * 132 + l * 8;

        int e = e_begin;
        while (e < e_end) {
            int c[8]; float v[8];
#pragma unroll
            for (int i = 0; i < 8; ++i) {
                int ei = e + i;
                int q  = min(ei, e_end - 1);
                c[i] = cols[q];
                v[i] = (ei < e_end) ? vals[q] : 0.f;
            }
            uint4 p[8];
#pragma unroll
            for (int i = 0; i < 8; ++i)
                p[i] = *(const uint4*)(xbB + (((unsigned)c[i] << 8) | loff));
#pragma unroll
            for (int i = 0; i < 8; ++i) {
                int ei = e + i;
                while (cur < 15 && ei >= rp_next) {    // rare: node advance
                    cur++; rp_next = rpS[cur + 1];
                    dst = nbAcc + cur * 132 + l * 8;
                }
                f32x2_t vv = {v[i], v[i]};
                f32x2_t t0 = vv * (f32x2_t){bflo(p[i].x), bfhi(p[i].x)};
                f32x2_t t1 = vv * (f32x2_t){bflo(p[i].y), bfhi(p[i].y)};
                f32x2_t t2 = vv * (f32x2_t){bflo(p[i].z), bfhi(p[i].z)};
                f32x2_t t3 = vv * (f32x2_t){bflo(p[i].w), bfhi(p[i].w)};
                atomicAdd(&dst[0], t0.x); atomicAdd(&dst[1], t0.y);
                atomicAdd(&dst[2], t1.x); atomicAdd(&dst[3], t1.y);
                atomicAdd(&dst[4], t2.x); atomicAdd(&dst[5], t2.y);
                atomicAdd(&dst[6], t3.x); atomicAdd(&dst[7], t3.y);
            }
            e += 8;
        }
    }
    __syncthreads();

    // ---------------- phase 2: gemm + normalize ----------------
    int m    = lane & 15;
    int quad = lane >> 4;
    int r0   = blockIdx.x * 16;

    int arow = min(r0 + m, Nn - 1);
    const bf16x8_t* Ax = (const bf16x8_t*)(xbB + (size_t)arow * 256);

    bf16x8_t a[8];
#pragma unroll
    for (int ks = 0; ks < 4; ++ks) a[ks] = Ax[ks * 4 + quad];
#pragma unroll
    for (int ks = 0; ks < 4; ++ks) {
        const float* src = nbAcc + m * 132 + ks * 32 + quad * 8;
        float4 f0 = *(const float4*)src;
        float4 f1 = *(const float4*)(src + 4);
        uint4 u;
        u.x = pack2(f0.x, f0.y); u.y = pack2(f0.z, f0.w);
        u.z = pack2(f1.x, f1.y); u.w = pack2(f1.z, f1.w);
        a[4 + ks] = *(bf16x8_t*)&u;
    }

    f32x4_t acc[2];
    float bc[2];
#pragma unroll
    for (int j = 0; j < 2; ++j) {
        int t = w * 2 + j;
        acc[j] = (f32x4_t){0.f, 0.f, 0.f, 0.f};
        bc[j]  = b[t * 16 + m];
#pragma unroll
        for (int ks = 0; ks < 8; ++ks) {
            acc[j] = __builtin_amdgcn_mfma_f32_16x16x32_bf16(
                a[ks], Wf[(t * 8 + ks) * 64 + lane], acc[j], 0, 0, 0);
        }
    }

    float sq[4] = {0.f, 0.f, 0.f, 0.f};
#pragma unroll
    for (int j = 0; j < 2; ++j)
#pragma unroll
        for (int r = 0; r < 4; ++r) {
            float u = acc[j][r] + bc[j];
            sq[r] += u * u;
        }
#pragma unroll
    for (int off = 1; off <= 8; off <<= 1) {
#pragma unroll
        for (int r = 0; r < 4; ++r) sq[r] += __shfl_xor(sq[r], off, 64);
    }
    if (m == 0) {
#pragma unroll
        for (int r = 0; r < 4; ++r) sqLDS[quad * 4 + r][w] = sq[r];
    }
    __syncthreads();

    float scale[4];
#pragma unroll
    for (int r = 0; r < 4; ++r) {
        const float4 q4 = *(const float4*)sqLDS[quad * 4 + r];
        float tot = q4.x + q4.y + q4.z + q4.w;
        scale[r] = 1.f / fmaxf(sqrtf(tot), 1e-12f);
    }

#pragma unroll
    for (int r = 0; r < 4; ++r) {
        int row = r0 + quad * 4 + r;
        if (row < Nn) {
            float* orow = out + (size_t)row * 128;
#pragma unroll
            for (int j = 0; j < 2; ++j) {
                int t = w * 2 + j;
                orow[t * 16 + m] = (acc[j][r] + bc[j]) * scale[r];
            }
        }
    }
}

extern "C" void kernel_launch(void* const* d_in, const int* in_sizes, int n_in,
                              void* d_out, int out_size, void* d_ws, size_t ws_size,
                              hipStream_t stream) {
    const float* x    = (const float*)d_in[0];
    const int*   rows = (const int*)  d_in[1];
    const int*   cols = (const int*)  d_in[2];
    const float* vals = (const float*)d_in[3];
    const float* W    = (const float*)d_in[4];
    const float* b    = (const float*)d_in[5];
    float*       out  = (float*)d_out;

    const int Nn = in_sizes[0] / 128;    // 100000
    const int Ee = in_sizes[1];          // 1600000

    char*  ws      = (char*)d_ws;
    int*   row_ptr = (int*)ws;
    uint4* Wf      = (uint4*)(ws + 448 * 1024);
    uint4* xb      = (uint4*)(ws + 640 * 1024);

    const int xcast_blks  = (Nn * 16 + 255) / 256;   // 6250
    const int rowptr_blks = (Nn + 1 + 255) / 256;    // 391
    const int wcast_blks  = 16;

    prep_kernel<<<xcast_blks + rowptr_blks + wcast_blks, 256, 0, stream>>>(
        x, xb, rows, row_ptr, W, Wf, Nn, Ee, xcast_blks, rowptr_blks);
    fused_kernel<<<(Nn + 15) / 16, 256, 0, stream>>>(
        row_ptr, cols, vals, (const char*)xb,
        (const bf16x8_t*)Wf, b, out, Nn);
}